// Round 2
// baseline (268.184 us; speedup 1.0000x reference)
//
#include <hip/hip_runtime.h>
#include <hip/hip_bf16.h>
#include <math.h>

using bf16x8 = __attribute__((ext_vector_type(8))) short;
using f32x4  = __attribute__((ext_vector_type(4))) float;

#define MFMA16(a,b,c) __builtin_amdgcn_mfma_f32_16x16x32_bf16(a,b,c,0,0,0)

// direct global->LDS 16B async copy; LDS dest must be wave-uniform base (+lane*16 by HW)
#define GLOAD_LDS16(g, s) __builtin_amdgcn_global_load_lds( \
    (const __attribute__((address_space(1))) unsigned int*)(const void*)(g), \
    (__attribute__((address_space(3))) unsigned int*)(void*)(s), 16, 0, 0)

static __device__ __forceinline__ short f2bf(float f) {
    __hip_bfloat16 h = __float2bfloat16(f);
    return *reinterpret_cast<short*>(&h);
}

// ---------------- prep: fp32 -> bf16 casts (grid-stride over float4 units) ----------------
__global__ void prep_cast(const float* q, const float* k, const float* v,
                          const float* wq, const float* wk, const float* wv, const float* wo,
                          short* xq, short* xk, short* xv,
                          short* bwq, short* bwk, short* bwv, short* bwo) {
    const long NBIG = 1L << 20;   // 4M elems / 4
    const long NW   = 1L << 18;   // 1M elems / 4
    const long total = 3*NBIG + 4*NW;
    for (long i = (long)blockIdx.x*blockDim.x + threadIdx.x; i < total; i += (long)gridDim.x*blockDim.x) {
        const float* src; short* dst; long j = i;
        if (j < NBIG)              { src = q;  dst = xq;  }
        else if ((j -= NBIG) < NBIG) { src = k;  dst = xk;  }
        else if ((j -= NBIG) < NBIG) { src = v;  dst = xv;  }
        else if ((j -= NBIG) < NW)   { src = wq; dst = bwq; }
        else if ((j -= NW) < NW)     { src = wk; dst = bwk; }
        else if ((j -= NW) < NW)     { src = wv; dst = bwv; }
        else { j -= NW;              src = wo; dst = bwo; }
        float4 f = reinterpret_cast<const float4*>(src)[j];
        ushort4 o;
        o.x = (ushort)f2bf(f.x); o.y = (ushort)f2bf(f.y);
        o.z = (ushort)f2bf(f.z); o.w = (ushort)f2bf(f.w);
        reinterpret_cast<ushort4*>(dst)[j] = o;
    }
}

// ---------------- RoPE tables, fp64 for accuracy: cos/sin[s][j], j=0..31 ----------------
__global__ void rope_table(float* cost, float* sint) {
    int i = blockIdx.x*blockDim.x + threadIdx.x;   // 0..65535
    int s = i >> 5, j = i & 31;
    double inv = pow(10000.0, -(double)j / 32.0);
    double a = (double)s * inv;
    cost[i] = (float)cos(a);
    sint[i] = (float)sin(a);
}

// ---------------- shared 128x128x(K=1024) bf16 GEMM core: C = A * B^T ----------------
// m97 structure: global_load_lds width-16 staging, 2 barriers/K-step, [128][32] linear LDS
__device__ __forceinline__ void gemm_tile(const short* A, const short* B,
                                          int brow, int bcol, f32x4 (&acc)[4][4]) {
    __shared__ __align__(16) short Al[128*32];
    __shared__ __align__(16) short Bl[128*32];
    const int t = threadIdx.x;
    const int l = t & 63, qi = l & 15, h = l >> 4;
    const int w = t >> 6, wr = w >> 1, wc = w & 1;
    const f32x4 z4 = {0.f, 0.f, 0.f, 0.f};
#pragma unroll
    for (int i = 0; i < 4; ++i)
#pragma unroll
        for (int j = 0; j < 4; ++j) acc[i][j] = z4;

    // staging geometry: wave w stages rows [w*32, w*32+32) of A and B tiles
    // instr cc covers rows w*32+cc*16+(l>>2); lane chunk (l&3)*8 elems; HW: lds_base+lane*16B
    const int srow = w*32 + (l >> 2);
    const int scol = (l & 3) << 3;
    const short* ga = A + (long)(brow + srow)*1024 + scol;
    const short* gb = B + (long)(bcol + srow)*1024 + scol;
    short* la = Al + w*32*32;    // wave-uniform
    short* lb = Bl + w*32*32;

    for (int kt = 0; kt < 32; ++kt) {
        __syncthreads();                       // prev iter's frag reads done
        GLOAD_LDS16(ga + (kt << 5),            la);
        GLOAD_LDS16(ga + (kt << 5) + 16*1024,  la + 16*32);
        GLOAD_LDS16(gb + (kt << 5),            lb);
        GLOAD_LDS16(gb + (kt << 5) + 16*1024,  lb + 16*32);
        __syncthreads();                       // vmcnt drained by barrier -> tile ready
        bf16x8 af[4], bfr[4];
#pragma unroll
        for (int mf = 0; mf < 4; ++mf)
            af[mf] = *(const bf16x8*)(Al + (wr*64 + mf*16 + qi)*32 + h*8);
#pragma unroll
        for (int nf = 0; nf < 4; ++nf)
            bfr[nf] = *(const bf16x8*)(Bl + (wc*64 + nf*16 + qi)*32 + h*8);
#pragma unroll
        for (int mf = 0; mf < 4; ++mf)
#pragma unroll
            for (int nf = 0; nf < 4; ++nf)
                acc[mf][nf] = MFMA16(af[mf], bfr[nf], acc[mf][nf]);
    }
}

// ---------------- QKV projection GEMM; z selects Q/K/V; fused bias + RoPE (+1/8 into Q) ----------------
__global__ __launch_bounds__(256, 2)
void gemm_qkv_kernel(const short* xq, const short* xk, const short* xv,
                     const short* wq, const short* wk, const short* wv,
                     const float* biq, const float* bik, const float* biv,
                     short* qo, short* ko, short* vo,
                     const float* cost, const float* sint) {
    const int mode = blockIdx.z;
    const short* A    = mode == 0 ? xq  : (mode == 1 ? xk  : xv);
    const short* B    = mode == 0 ? wq  : (mode == 1 ? wk  : wv);
    const float* bias = mode == 0 ? biq : (mode == 1 ? bik : biv);
    const int brow = blockIdx.x * 128, bcol = blockIdx.y * 128;
    f32x4 acc[4][4];
    gemm_tile(A, B, brow, bcol, acc);

    const int t = threadIdx.x;
    const int l = t & 63, qi = l & 15, h = l >> 4;
    const int w = t >> 6, wr = w >> 1, wc = w & 1;
    const int n0 = bcol + wc*64, m0 = brow + wr*64;

    if (mode < 2) {
        short* dst = mode == 0 ? qo : ko;
        const float sc = (mode == 0) ? 0.125f : 1.0f;   // fold 1/sqrt(Hd) into q
#pragma unroll
        for (int nf = 0; nf < 2; ++nf) {
            const int j = nf*16 + qi;                   // rope index 0..31 within head
            const float b0 = bias[n0 + nf*16 + qi];
            const float b1 = bias[n0 + (nf+2)*16 + qi];
#pragma unroll
            for (int mf = 0; mf < 4; ++mf) {
#pragma unroll
                for (int r = 0; r < 4; ++r) {
                    int m = m0 + mf*16 + 4*h + r;
                    int s = m & 2047;
                    float c  = cost[s*32 + j];
                    float si = sint[s*32 + j];
                    float x0 = acc[mf][nf  ][r] + b0;
                    float x1 = acc[mf][nf+2][r] + b1;
                    dst[(long)m*1024 + n0 + nf*16 + qi]      = f2bf((x0*c - x1*si) * sc);
                    dst[(long)m*1024 + n0 + (nf+2)*16 + qi]  = f2bf((x1*c + x0*si) * sc);
                }
            }
        }
    } else {
        // V: store transposed as [b][h][d][s] bf16, pack 4 consecutive s
#pragma unroll
        for (int mf = 0; mf < 4; ++mf) {
#pragma unroll
            for (int nf = 0; nf < 4; ++nf) {
                int col = n0 + nf*16 + qi;
                float bb = bias[col];
                int mbase = m0 + mf*16 + 4*h;
                int bb_  = mbase >> 11, s0 = mbase & 2047;
                int hh = col >> 6, d = col & 63;
                ushort4 pk;
                pk.x = (ushort)f2bf(acc[mf][nf][0] + bb);
                pk.y = (ushort)f2bf(acc[mf][nf][1] + bb);
                pk.z = (ushort)f2bf(acc[mf][nf][2] + bb);
                pk.w = (ushort)f2bf(acc[mf][nf][3] + bb);
                *(ushort4*)(vo + (long)((bb_*16 + hh)*64 + d)*2048 + s0) = pk;
            }
        }
    }
}

// ---------------- O projection GEMM -> fp32 out ----------------
__global__ __launch_bounds__(256, 2)
void gemm_o_kernel(const short* A, const short* B, const float* bias, float* out) {
    const int brow = blockIdx.x * 128, bcol = blockIdx.y * 128;
    f32x4 acc[4][4];
    gemm_tile(A, B, brow, bcol, acc);
    const int t = threadIdx.x;
    const int l = t & 63, qi = l & 15, h = l >> 4;
    const int w = t >> 6, wr = w >> 1, wc = w & 1;
    const int n0 = bcol + wc*64, m0 = brow + wr*64;
#pragma unroll
    for (int nf = 0; nf < 4; ++nf) {
        float bb = bias[n0 + nf*16 + qi];
#pragma unroll
        for (int mf = 0; mf < 4; ++mf) {
#pragma unroll
            for (int r = 0; r < 4; ++r) {
                int m = m0 + mf*16 + 4*h + r;
                out[(long)m*1024 + n0 + nf*16 + qi] = acc[mf][nf][r] + bb;
            }
        }
    }
}

// ---------------- flash attention ----------------
// q,k: [b][s][h][d] bf16 (q pre-scaled by 1/8). vT: [b][h][d][s] bf16. out: [b][s][h][d] bf16.
// 128 Q rows/block (4 waves x 32 rows). KV tiles of 64, double-buffered LDS,
// async-stage split (T14): issue loads after barrier, ds_write after compute.
__global__ __launch_bounds__(256, 2)
void attn_kernel(const short* qw, const short* kw, const short* vtw, short* ow) {
    __shared__ __align__(16) short Kl[2][64*64];
    __shared__ __align__(16) short Vl[2][64*64];
    __shared__ __align__(16) short Pl[4][32*64];
    const int t = threadIdx.x;
    const int w = t >> 6, l = t & 63, qi = l & 15, h = l >> 4;
    const int b = blockIdx.z, hh = blockIdx.y;
    const long qrow0 = (long)b*2048 + blockIdx.x*128 + w*32;
    short* myP = &Pl[w][0];

    bf16x8 bqf[2][2];
#pragma unroll
    for (int nf = 0; nf < 2; ++nf)
#pragma unroll
        for (int kf = 0; kf < 2; ++kf)
            bqf[nf][kf] = *(const bf16x8*)(qw + (qrow0 + nf*16 + qi)*1024 + hh*64 + kf*32 + h*8);

    const f32x4 z4 = {0.f, 0.f, 0.f, 0.f};
    f32x4 o[2][4];
#pragma unroll
    for (int mi = 0; mi < 2; ++mi)
#pragma unroll
        for (int nd = 0; nd < 4; ++nd) o[mi][nd] = z4;
    float mrun[2] = {-INFINITY, -INFINITY};
    float lrun[2] = {0.f, 0.f};

    const short* Kg = kw  + (long)b*2048*1024 + hh*64;
    const short* Vg = vtw + (long)(b*16 + hh)*64*2048;

    // per-thread staging coords (2 chunks of 16B for K and V each)
    const int c0 = t, c1 = t + 256;
    const int r0a = c0 >> 3, e0a = (c0 & 7) << 3;
    const int r0b = c1 >> 3, e0b = (c1 & 7) << 3;
    int4 kreg[2], vreg[2];

    // prologue: tile 0 -> regs -> LDS buf 0
    kreg[0] = *(const int4*)(Kg + (long)r0a*1024 + e0a);
    vreg[0] = *(const int4*)(Vg + (long)r0a*2048 + e0a);
    kreg[1] = *(const int4*)(Kg + (long)r0b*1024 + e0b);
    vreg[1] = *(const int4*)(Vg + (long)r0b*2048 + e0b);
    *(int4*)((char*)Kl[0] + (((r0a*64 + e0a)*2) ^ ((r0a & 7) << 4))) = kreg[0];
    *(int4*)((char*)Vl[0] + (((r0a*64 + e0a)*2) ^ ((r0a & 7) << 4))) = vreg[0];
    *(int4*)((char*)Kl[1 & 0] + (((r0b*64 + e0b)*2) ^ ((r0b & 7) << 4))) = kreg[1];
    *(int4*)((char*)Vl[0] + (((r0b*64 + e0b)*2) ^ ((r0b & 7) << 4))) = vreg[1];

    int cur = 0;
    for (int jt = 0; jt < 32; ++jt) {
        __syncthreads();   // buf[cur] staged & visible; prev reads of buf[cur^1] retired
        if (jt < 31) {     // issue next-tile loads AFTER barrier so its vmcnt(0) drain can't stall them
            kreg[0] = *(const int4*)(Kg + (long)((jt+1)*64 + r0a)*1024 + e0a);
            vreg[0] = *(const int4*)(Vg + (long)r0a*2048 + (jt+1)*64 + e0a);
            kreg[1] = *(const int4*)(Kg + (long)((jt+1)*64 + r0b)*1024 + e0b);
            vreg[1] = *(const int4*)(Vg + (long)r0b*2048 + (jt+1)*64 + e0b);
        }
        const short* Kc = Kl[cur];
        const short* Vc = Vl[cur];

        // S^T = K * Q^T : C row = j-local (4h+r+16mf), col = i-local (qi+16nf)
        f32x4 sc[4][2];
#pragma unroll
        for (int mf = 0; mf < 4; ++mf) { sc[mf][0] = z4; sc[mf][1] = z4; }
        __builtin_amdgcn_s_setprio(1);
#pragma unroll
        for (int kf = 0; kf < 2; ++kf) {
#pragma unroll
            for (int mf = 0; mf < 4; ++mf) {
                bf16x8 ka = *(const bf16x8*)((const char*)Kc +
                    ((((mf*16 + qi)*64 + kf*32 + h*8)*2) ^ ((qi & 7) << 4)));
                sc[mf][0] = MFMA16(ka, bqf[0][kf], sc[mf][0]);
                sc[mf][1] = MFMA16(ka, bqf[1][kf], sc[mf][1]);
            }
        }
        __builtin_amdgcn_s_setprio(0);

        float csc[2];
#pragma unroll
        for (int nf = 0; nf < 2; ++nf) {
            float tm = -INFINITY;
#pragma unroll
            for (int mf = 0; mf < 4; ++mf)
#pragma unroll
                for (int r = 0; r < 4; ++r) tm = fmaxf(tm, sc[mf][nf][r]);
            tm = fmaxf(tm, __shfl_xor(tm, 16));
            tm = fmaxf(tm, __shfl_xor(tm, 32));
            float mnew = fmaxf(mrun[nf], tm);
            float corr = __expf(mrun[nf] - mnew);
            float ts = 0.f;
#pragma unroll
            for (int mf = 0; mf < 4; ++mf) {
                float p0 = __expf(sc[mf][nf][0] - mnew);
                float p1 = __expf(sc[mf][nf][1] - mnew);
                float p2 = __expf(sc[mf][nf][2] - mnew);
                float p3 = __expf(sc[mf][nf][3] - mnew);
                ts += p0 + p1 + p2 + p3;
                ushort4 pk;
                pk.x = (ushort)f2bf(p0); pk.y = (ushort)f2bf(p1);
                pk.z = (ushort)f2bf(p2); pk.w = (ushort)f2bf(p3);
                *(ushort4*)((char*)myP +
                    ((((nf*16 + qi)*64 + mf*16 + 4*h)*2) ^ ((qi & 7) << 4))) = pk;
            }
            ts += __shfl_xor(ts, 16);
            ts += __shfl_xor(ts, 32);
            lrun[nf] = lrun[nf]*corr + ts;
            mrun[nf] = mnew;
            csc[nf] = corr;
        }

        // rescale O: factor for row i = mi*16+4h+r lives on lane with qi == 4h+r
#pragma unroll
        for (int mi = 0; mi < 2; ++mi)
#pragma unroll
            for (int r = 0; r < 4; ++r) {
                float f = __shfl(csc[mi], 4*h + r);
#pragma unroll
                for (int nd = 0; nd < 4; ++nd) o[mi][nd][r] *= f;
            }

        // O += P * V  (A=P from LDS, B=V^T from LDS)
        __builtin_amdgcn_s_setprio(1);
#pragma unroll
        for (int kf = 0; kf < 2; ++kf) {
            bf16x8 pa[2], vb[4];
#pragma unroll
            for (int mi = 0; mi < 2; ++mi)
                pa[mi] = *(const bf16x8*)((char*)myP +
                    ((((mi*16 + qi)*64 + kf*32 + h*8)*2) ^ ((qi & 7) << 4)));
#pragma unroll
            for (int nd = 0; nd < 4; ++nd)
                vb[nd] = *(const bf16x8*)((const char*)Vc +
                    ((((nd*16 + qi)*64 + kf*32 + h*8)*2) ^ ((qi & 7) << 4)));
#pragma unroll
            for (int mi = 0; mi < 2; ++mi)
#pragma unroll
                for (int nd = 0; nd < 4; ++nd)
                    o[mi][nd] = MFMA16(pa[mi], vb[nd], o[mi][nd]);
        }
        __builtin_amdgcn_s_setprio(0);

        // T14 write-late: stage next tile into the other buffer (safe: nobody reads it now)
        if (jt < 31) {
            int nb = cur ^ 1;
            *(int4*)((char*)Kl[nb] + (((r0a*64 + e0a)*2) ^ ((r0a & 7) << 4))) = kreg[0];
            *(int4*)((char*)Vl[nb] + (((r0a*64 + e0a)*2) ^ ((r0a & 7) << 4))) = vreg[0];
            *(int4*)((char*)Kl[nb] + (((r0b*64 + e0b)*2) ^ ((r0b & 7) << 4))) = kreg[1];
            *(int4*)((char*)Vl[nb] + (((r0b*64 + e0b)*2) ^ ((r0b & 7) << 4))) = vreg[1];
        }
        cur ^= 1;
    }

    float rinv[2] = {1.f/lrun[0], 1.f/lrun[1]};
#pragma unroll
    for (int mi = 0; mi < 2; ++mi)
#pragma unroll
        for (int r = 0; r < 4; ++r) {
            float f = __shfl(rinv[mi], 4*h + r);
#pragma unroll
            for (int nd = 0; nd < 4; ++nd)
                ow[(qrow0 + mi*16 + 4*h + r)*1024 + hh*64 + nd*16 + qi] =
                    f2bf(o[mi][nd][r] * f);
        }
}

// ---------------- launch ----------------
extern "C" void kernel_launch(void* const* d_in, const int* in_sizes, int n_in,
                              void* d_out, int out_size, void* d_ws, size_t ws_size,
                              hipStream_t stream) {
    const float* query = (const float*)d_in[0];
    const float* key_  = (const float*)d_in[1];
    const float* value = (const float*)d_in[2];
    const float* Wq = (const float*)d_in[3];
    const float* bq = (const float*)d_in[4];
    const float* Wk = (const float*)d_in[5];
    const float* bk = (const float*)d_in[6];
    const float* Wv = (const float*)d_in[7];
    const float* bv = (const float*)d_in[8];
    const float* Wo = (const float*)d_in[9];
    const float* bo = (const float*)d_in[10];
    float* out = (float*)d_out;

    char* ws = (char*)d_ws;
    const size_t MB = 1u << 20;
    short* xq  = (short*)(ws);              // 8 MB  [4096][1024] bf16
    short* xk  = (short*)(ws + 8*MB);
    short* xv  = (short*)(ws + 16*MB);
    short* wqb = (short*)(ws + 24*MB);      // 2 MB each
    short* wkb = (short*)(ws + 26*MB);
    short* wvb = (short*)(ws + 28*MB);
    short* wob = (short*)(ws + 30*MB);
    short* qws = (short*)(ws + 32*MB);      // [b][s][h][d] bf16, q pre-scaled
    short* kws = (short*)(ws + 40*MB);      // [b][s][h][d]
    short* vtw = (short*)(ws + 48*MB);      // [b][h][d][s]
    float* cost = (float*)(ws + 56*MB);     // [2048][32]
    float* sint = (float*)(ws + 56*MB + 2048*32*4);
    short* attn = xq;                       // alias: xq dead after projections

    hipLaunchKernelGGL(prep_cast, dim3(2048), dim3(256), 0, stream,
                       query, key_, value, Wq, Wk, Wv, Wo,
                       xq, xk, xv, wqb, wkb, wvb, wob);
    hipLaunchKernelGGL(rope_table, dim3(256), dim3(256), 0, stream, cost, sint);
    hipLaunchKernelGGL(gemm_qkv_kernel, dim3(32, 8, 3), dim3(256), 0, stream,
                       xq, xk, xv, wqb, wkb, wvb, bq, bk, bv,
                       qws, kws, vtw, cost, sint);
    hipLaunchKernelGGL(attn_kernel, dim3(16, 16, 2), dim3(256), 0, stream,
                       qws, kws, vtw, attn);
    hipLaunchKernelGGL(gemm_o_kernel, dim3(32, 8), dim3(256), 0, stream,
                       attn, wob, bo, out);
}

// Round 3
// 246.313 us; speedup vs baseline: 1.0888x; 1.0888x over previous
//
#include <hip/hip_runtime.h>
#include <hip/hip_bf16.h>
#include <math.h>

using bf16x8 = __attribute__((ext_vector_type(8))) short;
using f32x4  = __attribute__((ext_vector_type(4))) float;

#define MFMA16(a,b,c) __builtin_amdgcn_mfma_f32_16x16x32_bf16(a,b,c,0,0,0)

// direct global->LDS 16B async copy; LDS dest must be wave-uniform base (+lane*16 by HW)
#define GLOAD_LDS16(g, s) __builtin_amdgcn_global_load_lds( \
    (const __attribute__((address_space(1))) unsigned int*)(const void*)(g), \
    (__attribute__((address_space(3))) unsigned int*)(void*)(s), 16, 0, 0)

static __device__ __forceinline__ short f2bf(float f) {
    __hip_bfloat16 h = __float2bfloat16(f);
    return *reinterpret_cast<short*>(&h);
}

// ---------------- prep: fp32 -> bf16 casts (grid-stride over float4 units) ----------------
__global__ void prep_cast(const float* q, const float* k, const float* v,
                          const float* wq, const float* wk, const float* wv, const float* wo,
                          short* xq, short* xk, short* xv,
                          short* bwq, short* bwk, short* bwv, short* bwo) {
    const long NBIG = 1L << 20;   // 4M elems / 4
    const long NW   = 1L << 18;   // 1M elems / 4
    const long total = 3*NBIG + 4*NW;
    for (long i = (long)blockIdx.x*blockDim.x + threadIdx.x; i < total; i += (long)gridDim.x*blockDim.x) {
        const float* src; short* dst; long j = i;
        if (j < NBIG)              { src = q;  dst = xq;  }
        else if ((j -= NBIG) < NBIG) { src = k;  dst = xk;  }
        else if ((j -= NBIG) < NBIG) { src = v;  dst = xv;  }
        else if ((j -= NBIG) < NW)   { src = wq; dst = bwq; }
        else if ((j -= NW) < NW)     { src = wk; dst = bwk; }
        else if ((j -= NW) < NW)     { src = wv; dst = bwv; }
        else { j -= NW;              src = wo; dst = bwo; }
        float4 f = reinterpret_cast<const float4*>(src)[j];
        ushort4 o;
        o.x = (ushort)f2bf(f.x); o.y = (ushort)f2bf(f.y);
        o.z = (ushort)f2bf(f.z); o.w = (ushort)f2bf(f.w);
        reinterpret_cast<ushort4*>(dst)[j] = o;
    }
}

// ---------------- RoPE tables, fp64 for accuracy: cos/sin[s][j], j=0..31 ----------------
__global__ void rope_table(float* cost, float* sint) {
    int i = blockIdx.x*blockDim.x + threadIdx.x;   // 0..65535
    int s = i >> 5, j = i & 31;
    double inv = pow(10000.0, -(double)j / 32.0);
    double a = (double)s * inv;
    cost[i] = (float)cos(a);
    sint[i] = (float)sin(a);
}

// ---------------- shared 128x128x(K=1024) bf16 GEMM core: C = A * B^T ----------------
// 2-phase prefetch (T3-minimum): dbuf LDS, issue next tile's global_load_lds BEFORE
// compute of current tile, one vmcnt(0)+barrier per K-step.
__device__ __forceinline__ void gemm_tile(const short* A, const short* B,
                                          int brow, int bcol, f32x4 (&acc)[4][4]) {
    __shared__ __align__(16) short Al[2][128*32];
    __shared__ __align__(16) short Bl[2][128*32];
    const int t = threadIdx.x;
    const int l = t & 63, qi = l & 15, h = l >> 4;
    const int w = t >> 6, wr = w >> 1, wc = w & 1;
    const f32x4 z4 = {0.f, 0.f, 0.f, 0.f};
#pragma unroll
    for (int i = 0; i < 4; ++i)
#pragma unroll
        for (int j = 0; j < 4; ++j) acc[i][j] = z4;

    // staging geometry: wave w stages rows [w*32, w*32+32); lane covers row w*32+(l>>2),
    // 8-elem chunk (l&3)*8; HW writes lds_base + lane*16B linearly -> matches [row][32] layout
    const int srow = w*32 + (l >> 2);
    const int scol = (l & 3) << 3;
    const short* ga = A + (long)(brow + srow)*1024 + scol;
    const short* gb = B + (long)(bcol + srow)*1024 + scol;
    const int lo = w*32*32;   // wave-uniform LDS elem offset

    // prologue: stage tile 0 -> buf 0
    GLOAD_LDS16(ga,            Al[0] + lo);
    GLOAD_LDS16(ga + 16*1024,  Al[0] + lo + 16*32);
    GLOAD_LDS16(gb,            Bl[0] + lo);
    GLOAD_LDS16(gb + 16*1024,  Bl[0] + lo + 16*32);
    asm volatile("s_waitcnt vmcnt(0)");
    __syncthreads();

    int cur = 0;
    for (int kt = 0; kt < 32; ++kt) {
        // issue next-tile loads first: they fly while we ds_read + MFMA this tile
        if (kt < 31) {
            int nb = cur ^ 1;
            GLOAD_LDS16(ga + ((kt+1) << 5),            Al[nb] + lo);
            GLOAD_LDS16(ga + ((kt+1) << 5) + 16*1024,  Al[nb] + lo + 16*32);
            GLOAD_LDS16(gb + ((kt+1) << 5),            Bl[nb] + lo);
            GLOAD_LDS16(gb + ((kt+1) << 5) + 16*1024,  Bl[nb] + lo + 16*32);
        }
        bf16x8 af[4], bfr[4];
#pragma unroll
        for (int mf = 0; mf < 4; ++mf)
            af[mf] = *(const bf16x8*)(Al[cur] + (wr*64 + mf*16 + qi)*32 + h*8);
#pragma unroll
        for (int nf = 0; nf < 4; ++nf)
            bfr[nf] = *(const bf16x8*)(Bl[cur] + (wc*64 + nf*16 + qi)*32 + h*8);
        __builtin_amdgcn_s_setprio(1);
#pragma unroll
        for (int mf = 0; mf < 4; ++mf)
#pragma unroll
            for (int nf = 0; nf < 4; ++nf)
                acc[mf][nf] = MFMA16(af[mf], bfr[nf], acc[mf][nf]);
        __builtin_amdgcn_s_setprio(0);
        asm volatile("s_waitcnt vmcnt(0)");   // next tile landed
        __syncthreads();                      // all waves past reads of buf[cur]
        cur ^= 1;
    }
}

// ---------------- QKV projection GEMM; z selects Q/K/V; fused bias + RoPE (+1/8 into Q) ----------------
__global__ __launch_bounds__(256, 3)
void gemm_qkv_kernel(const short* xq, const short* xk, const short* xv,
                     const short* wq, const short* wk, const short* wv,
                     const float* biq, const float* bik, const float* biv,
                     short* qo, short* ko, short* vo,
                     const float* cost, const float* sint) {
    const int mode = blockIdx.z;
    const short* A    = mode == 0 ? xq  : (mode == 1 ? xk  : xv);
    const short* B    = mode == 0 ? wq  : (mode == 1 ? wk  : wv);
    const float* bias = mode == 0 ? biq : (mode == 1 ? bik : biv);
    const int brow = blockIdx.x * 128, bcol = blockIdx.y * 128;
    f32x4 acc[4][4];
    gemm_tile(A, B, brow, bcol, acc);

    const int t = threadIdx.x;
    const int l = t & 63, qi = l & 15, h = l >> 4;
    const int w = t >> 6, wr = w >> 1, wc = w & 1;
    const int n0 = bcol + wc*64, m0 = brow + wr*64;

    if (mode < 2) {
        short* dst = mode == 0 ? qo : ko;
        const float sc = (mode == 0) ? 0.125f : 1.0f;   // fold 1/sqrt(Hd) into q
#pragma unroll
        for (int nf = 0; nf < 2; ++nf) {
            const int j = nf*16 + qi;                   // rope index 0..31 within head
            const float b0 = bias[n0 + nf*16 + qi];
            const float b1 = bias[n0 + (nf+2)*16 + qi];
#pragma unroll
            for (int mf = 0; mf < 4; ++mf) {
#pragma unroll
                for (int r = 0; r < 4; ++r) {
                    int m = m0 + mf*16 + 4*h + r;
                    int s = m & 2047;
                    float c  = cost[s*32 + j];
                    float si = sint[s*32 + j];
                    float x0 = acc[mf][nf  ][r] + b0;
                    float x1 = acc[mf][nf+2][r] + b1;
                    dst[(long)m*1024 + n0 + nf*16 + qi]      = f2bf((x0*c - x1*si) * sc);
                    dst[(long)m*1024 + n0 + (nf+2)*16 + qi]  = f2bf((x1*c + x0*si) * sc);
                }
            }
        }
    } else {
        // V: store transposed as [b][h][d][s] bf16, pack 4 consecutive s
#pragma unroll
        for (int mf = 0; mf < 4; ++mf) {
#pragma unroll
            for (int nf = 0; nf < 4; ++nf) {
                int col = n0 + nf*16 + qi;
                float bb = bias[col];
                int mbase = m0 + mf*16 + 4*h;
                int bb_  = mbase >> 11, s0 = mbase & 2047;
                int hh = col >> 6, d = col & 63;
                ushort4 pk;
                pk.x = (ushort)f2bf(acc[mf][nf][0] + bb);
                pk.y = (ushort)f2bf(acc[mf][nf][1] + bb);
                pk.z = (ushort)f2bf(acc[mf][nf][2] + bb);
                pk.w = (ushort)f2bf(acc[mf][nf][3] + bb);
                *(ushort4*)(vo + (long)((bb_*16 + hh)*64 + d)*2048 + s0) = pk;
            }
        }
    }
}

// ---------------- O projection GEMM -> fp32 out ----------------
__global__ __launch_bounds__(256, 3)
void gemm_o_kernel(const short* A, const short* B, const float* bias, float* out) {
    const int brow = blockIdx.x * 128, bcol = blockIdx.y * 128;
    f32x4 acc[4][4];
    gemm_tile(A, B, brow, bcol, acc);
    const int t = threadIdx.x;
    const int l = t & 63, qi = l & 15, h = l >> 4;
    const int w = t >> 6, wr = w >> 1, wc = w & 1;
    const int n0 = bcol + wc*64, m0 = brow + wr*64;
#pragma unroll
    for (int nf = 0; nf < 4; ++nf) {
        float bb = bias[n0 + nf*16 + qi];
#pragma unroll
        for (int mf = 0; mf < 4; ++mf) {
#pragma unroll
            for (int r = 0; r < 4; ++r) {
                int m = m0 + mf*16 + 4*h + r;
                out[(long)m*1024 + n0 + nf*16 + qi] = acc[mf][nf][r] + bb;
            }
        }
    }
}

// ---------------- flash attention (round-1 structure + setprio) ----------------
// q,k: [b][s][h][d] bf16 (q pre-scaled by 1/8). vT: [b][h][d][s] bf16. out: [b][s][h][d] bf16.
// Block: 128 Q rows of one (b,h). 4 waves x 32 rows. KV tiles of 64, single-buffered.
// Swapped QK^T (mfma(K, Q^T)) -> lane q holds softmax rows locally; P via swizzled LDS.
__global__ __launch_bounds__(256, 2)
void attn_kernel(const short* qw, const short* kw, const short* vtw, short* ow) {
    __shared__ __align__(16) short Kl[64*64];
    __shared__ __align__(16) short Vl[64*64];
    __shared__ __align__(16) short Pl[4][32*64];
    const int t = threadIdx.x;
    const int w = t >> 6, l = t & 63, qi = l & 15, h = l >> 4;
    const int b = blockIdx.z, hh = blockIdx.y;
    const long qrow0 = (long)b*2048 + blockIdx.x*128 + w*32;
    short* myP = &Pl[w][0];

    bf16x8 bqf[2][2];
#pragma unroll
    for (int nf = 0; nf < 2; ++nf)
#pragma unroll
        for (int kf = 0; kf < 2; ++kf)
            bqf[nf][kf] = *(const bf16x8*)(qw + (qrow0 + nf*16 + qi)*1024 + hh*64 + kf*32 + h*8);

    const f32x4 z4 = {0.f, 0.f, 0.f, 0.f};
    f32x4 o[2][4];
#pragma unroll
    for (int mi = 0; mi < 2; ++mi)
#pragma unroll
        for (int nd = 0; nd < 4; ++nd) o[mi][nd] = z4;
    float mrun[2] = {-INFINITY, -INFINITY};
    float lrun[2] = {0.f, 0.f};

    const short* Kg = kw  + (long)b*2048*1024 + hh*64;
    const short* Vg = vtw + (long)(b*16 + hh)*64*2048;

    for (int jt = 0; jt < 32; ++jt) {
        __syncthreads();
#pragma unroll
        for (int cc = 0; cc < 2; ++cc) {
            int c  = t + (cc << 8);            // 0..511
            int r0 = c >> 3, e0 = (c & 7) << 3;
            int4 kv = *(const int4*)(Kg + (long)(jt*64 + r0)*1024 + e0);
            int4 vv = *(const int4*)(Vg + (long)r0*2048 + jt*64 + e0);
            *(int4*)((char*)Kl + (((r0*64 + e0)*2) ^ ((r0 & 7) << 4))) = kv;
            *(int4*)((char*)Vl + (((r0*64 + e0)*2) ^ ((r0 & 7) << 4))) = vv;
        }
        __syncthreads();

        // S^T = K * Q^T : C row = j-local (4h+r+16mf), col = i-local (qi+16nf)
        f32x4 sc[4][2];
#pragma unroll
        for (int mf = 0; mf < 4; ++mf) { sc[mf][0] = z4; sc[mf][1] = z4; }
        __builtin_amdgcn_s_setprio(1);
#pragma unroll
        for (int kf = 0; kf < 2; ++kf) {
#pragma unroll
            for (int mf = 0; mf < 4; ++mf) {
                bf16x8 ka = *(const bf16x8*)((char*)Kl +
                    ((((mf*16 + qi)*64 + kf*32 + h*8)*2) ^ ((qi & 7) << 4)));
                sc[mf][0] = MFMA16(ka, bqf[0][kf], sc[mf][0]);
                sc[mf][1] = MFMA16(ka, bqf[1][kf], sc[mf][1]);
            }
        }
        __builtin_amdgcn_s_setprio(0);

        float csc[2];
#pragma unroll
        for (int nf = 0; nf < 2; ++nf) {
            float tm = -INFINITY;
#pragma unroll
            for (int mf = 0; mf < 4; ++mf)
#pragma unroll
                for (int r = 0; r < 4; ++r) tm = fmaxf(tm, sc[mf][nf][r]);
            tm = fmaxf(tm, __shfl_xor(tm, 16));
            tm = fmaxf(tm, __shfl_xor(tm, 32));
            float mnew = fmaxf(mrun[nf], tm);
            float corr = __expf(mrun[nf] - mnew);
            float ts = 0.f;
#pragma unroll
            for (int mf = 0; mf < 4; ++mf) {
                float p0 = __expf(sc[mf][nf][0] - mnew);
                float p1 = __expf(sc[mf][nf][1] - mnew);
                float p2 = __expf(sc[mf][nf][2] - mnew);
                float p3 = __expf(sc[mf][nf][3] - mnew);
                ts += p0 + p1 + p2 + p3;
                ushort4 pk;
                pk.x = (ushort)f2bf(p0); pk.y = (ushort)f2bf(p1);
                pk.z = (ushort)f2bf(p2); pk.w = (ushort)f2bf(p3);
                *(ushort4*)((char*)myP +
                    ((((nf*16 + qi)*64 + mf*16 + 4*h)*2) ^ ((qi & 7) << 4))) = pk;
            }
            ts += __shfl_xor(ts, 16);
            ts += __shfl_xor(ts, 32);
            lrun[nf] = lrun[nf]*corr + ts;
            mrun[nf] = mnew;
            csc[nf] = corr;
        }

        // rescale O: factor for row i = mi*16+4h+r lives on lane with qi == 4h+r
#pragma unroll
        for (int mi = 0; mi < 2; ++mi)
#pragma unroll
            for (int r = 0; r < 4; ++r) {
                float f = __shfl(csc[mi], 4*h + r);
#pragma unroll
                for (int nd = 0; nd < 4; ++nd) o[mi][nd][r] *= f;
            }

        // O += P * V  (A=P from LDS, B=V^T from LDS)
        __builtin_amdgcn_s_setprio(1);
#pragma unroll
        for (int kf = 0; kf < 2; ++kf) {
            bf16x8 pa[2], vb[4];
#pragma unroll
            for (int mi = 0; mi < 2; ++mi)
                pa[mi] = *(const bf16x8*)((char*)myP +
                    ((((mi*16 + qi)*64 + kf*32 + h*8)*2) ^ ((qi & 7) << 4)));
#pragma unroll
            for (int nd = 0; nd < 4; ++nd)
                vb[nd] = *(const bf16x8*)((char*)Vl +
                    ((((nd*16 + qi)*64 + kf*32 + h*8)*2) ^ ((qi & 7) << 4)));
#pragma unroll
            for (int mi = 0; mi < 2; ++mi)
#pragma unroll
                for (int nd = 0; nd < 4; ++nd)
                    o[mi][nd] = MFMA16(pa[mi], vb[nd], o[mi][nd]);
        }
        __builtin_amdgcn_s_setprio(0);
    }

    float rinv[2] = {1.f/lrun[0], 1.f/lrun[1]};
#pragma unroll
    for (int mi = 0; mi < 2; ++mi)
#pragma unroll
        for (int r = 0; r < 4; ++r) {
            float f = __shfl(rinv[mi], 4*h + r);
#pragma unroll
            for (int nd = 0; nd < 4; ++nd)
                ow[(qrow0 + mi*16 + 4*h + r)*1024 + hh*64 + nd*16 + qi] =
                    f2bf(o[mi][nd][r] * f);
        }
}

// ---------------- launch ----------------
extern "C" void kernel_launch(void* const* d_in, const int* in_sizes, int n_in,
                              void* d_out, int out_size, void* d_ws, size_t ws_size,
                              hipStream_t stream) {
    const float* query = (const float*)d_in[0];
    const float* key_  = (const float*)d_in[1];
    const float* value = (const float*)d_in[2];
    const float* Wq = (const float*)d_in[3];
    const float* bq = (const float*)d_in[4];
    const float* Wk = (const float*)d_in[5];
    const float* bk = (const float*)d_in[6];
    const float* Wv = (const float*)d_in[7];
    const float* bv = (const float*)d_in[8];
    const float* Wo = (const float*)d_in[9];
    const float* bo = (const float*)d_in[10];
    float* out = (float*)d_out;

    char* ws = (char*)d_ws;
    const size_t MB = 1u << 20;
    short* xq  = (short*)(ws);              // 8 MB  [4096][1024] bf16
    short* xk  = (short*)(ws + 8*MB);
    short* xv  = (short*)(ws + 16*MB);
    short* wqb = (short*)(ws + 24*MB);      // 2 MB each
    short* wkb = (short*)(ws + 26*MB);
    short* wvb = (short*)(ws + 28*MB);
    short* wob = (short*)(ws + 30*MB);
    short* qws = (short*)(ws + 32*MB);      // [b][s][h][d] bf16, q pre-scaled
    short* kws = (short*)(ws + 40*MB);      // [b][s][h][d]
    short* vtw = (short*)(ws + 48*MB);      // [b][h][d][s]
    float* cost = (float*)(ws + 56*MB);     // [2048][32]
    float* sint = (float*)(ws + 56*MB + 2048*32*4);
    short* attn = xq;                       // alias: xq dead after projections

    hipLaunchKernelGGL(prep_cast, dim3(2048), dim3(256), 0, stream,
                       query, key_, value, Wq, Wk, Wv, Wo,
                       xq, xk, xv, wqb, wkb, wvb, wob);
    hipLaunchKernelGGL(rope_table, dim3(256), dim3(256), 0, stream, cost, sint);
    hipLaunchKernelGGL(gemm_qkv_kernel, dim3(32, 8, 3), dim3(256), 0, stream,
                       xq, xk, xv, wqb, wkb, wvb, bq, bk, bv,
                       qws, kws, vtw, cost, sint);
    hipLaunchKernelGGL(attn_kernel, dim3(16, 16, 2), dim3(256), 0, stream,
                       qws, kws, vtw, attn);
    hipLaunchKernelGGL(gemm_o_kernel, dim3(32, 8), dim3(256), 0, stream,
                       attn, wob, bo, out);
}

// Round 4
// 238.621 us; speedup vs baseline: 1.1239x; 1.0322x over previous
//
#include <hip/hip_runtime.h>
#include <hip/hip_bf16.h>
#include <math.h>

using bf16x8 = __attribute__((ext_vector_type(8))) short;
using f32x4  = __attribute__((ext_vector_type(4))) float;
using f32x16 = __attribute__((ext_vector_type(16))) float;

#define MFMA16(a,b,c) __builtin_amdgcn_mfma_f32_16x16x32_bf16(a,b,c,0,0,0)
#define MFMA32(a,b,c) __builtin_amdgcn_mfma_f32_32x32x16_bf16(a,b,c,0,0,0)

// direct global->LDS 16B async copy; LDS dest must be wave-uniform base (+lane*16 by HW)
#define GLOAD_LDS16(g, s) __builtin_amdgcn_global_load_lds( \
    (const __attribute__((address_space(1))) unsigned int*)(const void*)(g), \
    (__attribute__((address_space(3))) unsigned int*)(void*)(s), 16, 0, 0)

static __device__ __forceinline__ short f2bf(float f) {
    __hip_bfloat16 h = __float2bfloat16(f);
    return *reinterpret_cast<short*>(&h);
}

// pack 2 f32 -> 2 bf16 in one dword (lo -> low half), RNE
static __device__ __forceinline__ int cvtpk(float lo, float hi) {
    int r;
    asm volatile("v_cvt_pk_bf16_f32 %0, %1, %2" : "=v"(r) : "v"(lo), "v"(hi));
    return r;
}

// ---------------- prep: fp32 -> bf16 casts (grid-stride over float4 units) ----------------
__global__ void prep_cast(const float* q, const float* k, const float* v,
                          const float* wq, const float* wk, const float* wv, const float* wo,
                          short* xq, short* xk, short* xv,
                          short* bwq, short* bwk, short* bwv, short* bwo) {
    const long NBIG = 1L << 20;   // 4M elems / 4
    const long NW   = 1L << 18;   // 1M elems / 4
    const long total = 3*NBIG + 4*NW;
    for (long i = (long)blockIdx.x*blockDim.x + threadIdx.x; i < total; i += (long)gridDim.x*blockDim.x) {
        const float* src; short* dst; long j = i;
        if (j < NBIG)              { src = q;  dst = xq;  }
        else if ((j -= NBIG) < NBIG) { src = k;  dst = xk;  }
        else if ((j -= NBIG) < NBIG) { src = v;  dst = xv;  }
        else if ((j -= NBIG) < NW)   { src = wq; dst = bwq; }
        else if ((j -= NW) < NW)     { src = wk; dst = bwk; }
        else if ((j -= NW) < NW)     { src = wv; dst = bwv; }
        else { j -= NW;              src = wo; dst = bwo; }
        float4 f = reinterpret_cast<const float4*>(src)[j];
        ushort4 o;
        o.x = (ushort)f2bf(f.x); o.y = (ushort)f2bf(f.y);
        o.z = (ushort)f2bf(f.z); o.w = (ushort)f2bf(f.w);
        reinterpret_cast<ushort4*>(dst)[j] = o;
    }
}

// ---------------- RoPE tables, fp64 for accuracy: cos/sin[s][j], j=0..31 ----------------
__global__ void rope_table(float* cost, float* sint) {
    int i = blockIdx.x*blockDim.x + threadIdx.x;   // 0..65535
    int s = i >> 5, j = i & 31;
    double inv = pow(10000.0, -(double)j / 32.0);
    double a = (double)s * inv;
    cost[i] = (float)cos(a);
    sint[i] = (float)sin(a);
}

// ---------------- shared 128x128x(K=1024) bf16 GEMM core: C = A * B^T ----------------
// 2-phase prefetch: dbuf LDS (passed in), issue next tile's global_load_lds BEFORE
// compute of current tile, one vmcnt(0)+barrier per K-step.
__device__ __forceinline__ void gemm_tile(const short* A, const short* B,
                                          int brow, int bcol, short* lds,
                                          f32x4 (&acc)[4][4]) {
    short* Al0 = lds;
    short* Al1 = lds + 4096;
    short* Bl0 = lds + 8192;
    short* Bl1 = lds + 12288;
    const int t = threadIdx.x;
    const int l = t & 63, qi = l & 15, h = l >> 4;
    const int w = t >> 6, wr = w >> 1, wc = w & 1;
    const f32x4 z4 = {0.f, 0.f, 0.f, 0.f};
#pragma unroll
    for (int i = 0; i < 4; ++i)
#pragma unroll
        for (int j = 0; j < 4; ++j) acc[i][j] = z4;

    const int srow = w*32 + (l >> 2);
    const int scol = (l & 3) << 3;
    const short* ga = A + (long)(brow + srow)*1024 + scol;
    const short* gb = B + (long)(bcol + srow)*1024 + scol;
    const int lo = w*32*32;   // wave-uniform LDS elem offset

    GLOAD_LDS16(ga,            Al0 + lo);
    GLOAD_LDS16(ga + 16*1024,  Al0 + lo + 16*32);
    GLOAD_LDS16(gb,            Bl0 + lo);
    GLOAD_LDS16(gb + 16*1024,  Bl0 + lo + 16*32);
    asm volatile("s_waitcnt vmcnt(0)");
    __syncthreads();

    int cur = 0;
    for (int kt = 0; kt < 32; ++kt) {
        if (kt < 31) {
            short* An = cur ? Al0 : Al1;
            short* Bn = cur ? Bl0 : Bl1;
            GLOAD_LDS16(ga + ((kt+1) << 5),            An + lo);
            GLOAD_LDS16(ga + ((kt+1) << 5) + 16*1024,  An + lo + 16*32);
            GLOAD_LDS16(gb + ((kt+1) << 5),            Bn + lo);
            GLOAD_LDS16(gb + ((kt+1) << 5) + 16*1024,  Bn + lo + 16*32);
        }
        const short* Ac = cur ? Al1 : Al0;
        const short* Bc = cur ? Bl1 : Bl0;
        bf16x8 af[4], bfr[4];
#pragma unroll
        for (int mf = 0; mf < 4; ++mf)
            af[mf] = *(const bf16x8*)(Ac + (wr*64 + mf*16 + qi)*32 + h*8);
#pragma unroll
        for (int nf = 0; nf < 4; ++nf)
            bfr[nf] = *(const bf16x8*)(Bc + (wc*64 + nf*16 + qi)*32 + h*8);
        __builtin_amdgcn_s_setprio(1);
#pragma unroll
        for (int mf = 0; mf < 4; ++mf)
#pragma unroll
            for (int nf = 0; nf < 4; ++nf)
                acc[mf][nf] = MFMA16(af[mf], bfr[nf], acc[mf][nf]);
        __builtin_amdgcn_s_setprio(0);
        asm volatile("s_waitcnt vmcnt(0)");
        __syncthreads();
        cur ^= 1;
    }
}

// ---------------- QKV projection GEMM; z selects Q/K/V; fused bias + RoPE (+1/8 into Q) ----------------
__global__ __launch_bounds__(256, 3)
void gemm_qkv_kernel(const short* xq, const short* xk, const short* xv,
                     const short* wq, const short* wk, const short* wv,
                     const float* biq, const float* bik, const float* biv,
                     short* qo, short* ko, short* vo,
                     const float* cost, const float* sint) {
    __shared__ __align__(16) short lds[16384];
    const int mode = blockIdx.z;
    const short* A    = mode == 0 ? xq  : (mode == 1 ? xk  : xv);
    const short* B    = mode == 0 ? wq  : (mode == 1 ? wk  : wv);
    const float* bias = mode == 0 ? biq : (mode == 1 ? bik : biv);
    const int brow = blockIdx.x * 128, bcol = blockIdx.y * 128;
    f32x4 acc[4][4];
    gemm_tile(A, B, brow, bcol, lds, acc);

    const int t = threadIdx.x;
    const int l = t & 63, qi = l & 15, h = l >> 4;
    const int w = t >> 6, wr = w >> 1, wc = w & 1;
    const int n0 = bcol + wc*64, m0 = brow + wr*64;

    if (mode < 2) {
        short* dst = mode == 0 ? qo : ko;
        const float sc = (mode == 0) ? 0.125f : 1.0f;   // fold 1/sqrt(Hd) into q
#pragma unroll
        for (int nf = 0; nf < 2; ++nf) {
            const int j = nf*16 + qi;                   // rope index 0..31 within head
            const float b0 = bias[n0 + nf*16 + qi];
            const float b1 = bias[n0 + (nf+2)*16 + qi];
#pragma unroll
            for (int mf = 0; mf < 4; ++mf) {
#pragma unroll
                for (int r = 0; r < 4; ++r) {
                    int m = m0 + mf*16 + 4*h + r;
                    int s = m & 2047;
                    float c  = cost[s*32 + j];
                    float si = sint[s*32 + j];
                    float x0 = acc[mf][nf  ][r] + b0;
                    float x1 = acc[mf][nf+2][r] + b1;
                    dst[(long)m*1024 + n0 + nf*16 + qi]      = f2bf((x0*c - x1*si) * sc);
                    dst[(long)m*1024 + n0 + (nf+2)*16 + qi]  = f2bf((x1*c + x0*si) * sc);
                }
            }
        }
    } else {
        // V: transpose 64x64 per wave through LDS, then coalesced stores to [b][h][d][s]
        __syncthreads();                    // gemm LDS free for reuse
        short* tb = lds + w*4096;           // 64x64 elems, wave-private
#pragma unroll
        for (int nf = 0; nf < 4; ++nf) {
            const int dl = nf*16 + qi;
            const float bb = bias[n0 + dl];
#pragma unroll
            for (int mf = 0; mf < 4; ++mf) {
#pragma unroll
                for (int r = 0; r < 4; ++r) {
                    const int sl = mf*16 + 4*h + r;
                    *(short*)((char*)tb + (((dl*64 + sl)*2) ^ ((dl & 7) << 4))) =
                        f2bf(acc[mf][nf][r] + bb);
                }
            }
        }
        // wave-internal LDS dependency: compiler inserts lgkmcnt waits
        const int hh2 = n0 >> 6;
        const int bb2 = m0 >> 11;
        const long s0g = (long)(m0 & 2047);
#pragma unroll
        for (int i = 0; i < 8; ++i) {
            const int c = l + (i << 6);
            const int dl = c >> 3, so = (c & 7) << 3;
            int4 vv = *(const int4*)((char*)tb + (((dl*64 + so)*2) ^ ((dl & 7) << 4)));
            *(int4*)(vo + (long)((bb2*16 + hh2)*64 + dl)*2048 + s0g + so) = vv;
        }
    }
}

// ---------------- O projection GEMM -> fp32 out ----------------
__global__ __launch_bounds__(256, 3)
void gemm_o_kernel(const short* A, const short* B, const float* bias, float* out) {
    __shared__ __align__(16) short lds[16384];
    const int brow = blockIdx.x * 128, bcol = blockIdx.y * 128;
    f32x4 acc[4][4];
    gemm_tile(A, B, brow, bcol, lds, acc);
    const int t = threadIdx.x;
    const int l = t & 63, qi = l & 15, h = l >> 4;
    const int w = t >> 6, wr = w >> 1, wc = w & 1;
    const int n0 = bcol + wc*64, m0 = brow + wr*64;
#pragma unroll
    for (int nf = 0; nf < 4; ++nf) {
        float bb = bias[n0 + nf*16 + qi];
#pragma unroll
        for (int mf = 0; mf < 4; ++mf) {
#pragma unroll
            for (int r = 0; r < 4; ++r) {
                int m = m0 + mf*16 + 4*h + r;
                out[(long)m*1024 + n0 + nf*16 + qi] = acc[mf][nf][r] + bb;
            }
        }
    }
}

// ---------------- flash attention, 32x32 MFMA, softmax fully lane-local ----------------
// q,k: [b][s][h][d] bf16 (q pre-scaled by 1/8). vT: [b][h][d][s] bf16. out: [b][s][h][d] bf16.
// Block: 128 q rows of one (b,h); 4 waves x 32 q-rows. KV tiles of 64.
// QK^T swapped (A=K, B=Q) -> C = S^T: lane q = lane&31 owns a q-row; kv split lane/lane+32.
// PV swapped (A=V^T, B=P^T) -> C = O^T: same q ownership; rescale/normalize lane-local.
__global__ __launch_bounds__(256, 2)
void attn_kernel(const short* qw, const short* kw, const short* vtw, short* ow) {
    __shared__ __align__(16) short Kl[64*64];   // [kv][d], XOR-swizzled rows
    __shared__ __align__(16) short Vl[64*64];   // [d][kv], XOR-swizzled rows
    const int t = threadIdx.x;
    const int w = t >> 6, l = t & 63;
    const int q5 = l & 31, hi = l >> 5;
    const int b = blockIdx.z, hh = blockIdx.y;
    const long qrow = (long)b*2048 + blockIdx.x*128 + w*32 + q5;

    // Q B-frags: slab s covers d = s*16 + hi*8 + e
    bf16x8 bqf[4];
#pragma unroll
    for (int s = 0; s < 4; ++s)
        bqf[s] = *(const bf16x8*)(qw + qrow*1024 + hh*64 + s*16 + hi*8);

    f32x16 o0, o1;
#pragma unroll
    for (int r = 0; r < 16; ++r) { o0[r] = 0.f; o1[r] = 0.f; }
    float mrun = -INFINITY, lrun = 0.f;

    const short* Kg = kw  + (long)b*2048*1024 + hh*64;
    const short* Vg = vtw + (long)(b*16 + hh)*64*2048;

    // staging coords: chunk c -> row c>>3, 8-elem offset (c&7)*8
    const int r0a = t >> 3,        e0a = (t & 7) << 3;
    const int r0b = (t+256) >> 3,  e0b = ((t+256) & 7) << 3;

    for (int jt = 0; jt < 32; ++jt) {
        __syncthreads();
        {
            int4 ka = *(const int4*)(Kg + (long)(jt*64 + r0a)*1024 + e0a);
            int4 va = *(const int4*)(Vg + (long)r0a*2048 + jt*64 + e0a);
            int4 kb = *(const int4*)(Kg + (long)(jt*64 + r0b)*1024 + e0b);
            int4 vb = *(const int4*)(Vg + (long)r0b*2048 + jt*64 + e0b);
            *(int4*)((char*)Kl + (((r0a*64 + e0a)*2) ^ ((r0a & 7) << 4))) = ka;
            *(int4*)((char*)Vl + (((r0a*64 + e0a)*2) ^ ((r0a & 7) << 4))) = va;
            *(int4*)((char*)Kl + (((r0b*64 + e0b)*2) ^ ((r0b & 7) << 4))) = kb;
            *(int4*)((char*)Vl + (((r0b*64 + e0b)*2) ^ ((r0b & 7) << 4))) = vb;
        }
        __syncthreads();

        // S^T: 2 kv-subtiles x 4 d-slabs
        f32x16 s0v, s1v;
#pragma unroll
        for (int r = 0; r < 16; ++r) { s0v[r] = 0.f; s1v[r] = 0.f; }
        __builtin_amdgcn_s_setprio(1);
#pragma unroll
        for (int s = 0; s < 4; ++s) {
            const int cb = (s*16 + hi*8) * 2;
            bf16x8 ka0 = *(const bf16x8*)((char*)Kl + (((q5*64*2) + cb) ^ ((q5 & 7) << 4)));
            bf16x8 ka1 = *(const bf16x8*)((char*)Kl + ((((32+q5)*64*2) + cb) ^ ((q5 & 7) << 4)));
            s0v = MFMA32(ka0, bqf[s], s0v);
            s1v = MFMA32(ka1, bqf[s], s1v);
        }
        __builtin_amdgcn_s_setprio(0);

        // online softmax: lane q5 (both hi halves) owns row q; kv halves exchanged via shfl_xor 32
        float tm = -INFINITY;
#pragma unroll
        for (int r = 0; r < 16; ++r) { tm = fmaxf(tm, s0v[r]); tm = fmaxf(tm, s1v[r]); }
        tm = fmaxf(tm, __shfl_xor(tm, 32));
        const float mnew = fmaxf(mrun, tm);
        const float corr = __expf(mrun - mnew);
        float ts = 0.f;
#pragma unroll
        for (int r = 0; r < 16; ++r) {
            s0v[r] = __expf(s0v[r] - mnew);
            s1v[r] = __expf(s1v[r] - mnew);
            ts += s0v[r] + s1v[r];
        }
        ts += __shfl_xor(ts, 32);
        lrun = lrun*corr + ts;
        mrun = mnew;
#pragma unroll
        for (int r = 0; r < 16; ++r) { o0[r] *= corr; o1[r] *= corr; }

        // P^T B-frags: slab s4 = 2*tt+ss covers kv = 32*tt + 16*ss + hi*8 + e.
        // Lane holds C rows kv=(r&3)+8*(r>>2)+4*hi; partner (lane^32) has the other half.
        bf16x8 pf[4];
#pragma unroll
        for (int tt = 0; tt < 2; ++tt) {
#pragma unroll
            for (int ss = 0; ss < 2; ++ss) {
                const int base = 8*ss;
                float p0, p1, p2, p3, p4, p5, p6, p7;
                if (tt == 0) {
                    p0=s0v[base+0]; p1=s0v[base+1]; p2=s0v[base+2]; p3=s0v[base+3];
                    p4=s0v[base+4]; p5=s0v[base+5]; p6=s0v[base+6]; p7=s0v[base+7];
                } else {
                    p0=s1v[base+0]; p1=s1v[base+1]; p2=s1v[base+2]; p3=s1v[base+3];
                    p4=s1v[base+4]; p5=s1v[base+5]; p6=s1v[base+6]; p7=s1v[base+7];
                }
                int X0 = cvtpk(p0, p1), Y0 = cvtpk(p2, p3);
                int X1 = cvtpk(p4, p5), Y1 = cvtpk(p6, p7);
                int sx0 = __shfl_xor(X0, 32), sy0 = __shfl_xor(Y0, 32);
                int sx1 = __shfl_xor(X1, 32), sy1 = __shfl_xor(Y1, 32);
                union { int i[4]; bf16x8 v; } u;
                u.i[0] = hi ? sx1 : X0;     // e0,e1
                u.i[1] = hi ? sy1 : Y0;     // e2,e3
                u.i[2] = hi ? X1  : sx0;    // e4,e5
                u.i[3] = hi ? Y1  : sy0;    // e6,e7
                pf[2*tt + ss] = u.v;
            }
        }

        // O^T += V^T * P^T
        __builtin_amdgcn_s_setprio(1);
#pragma unroll
        for (int s4 = 0; s4 < 4; ++s4) {
            const int cb = (s4*16 + hi*8) * 2;
            bf16x8 va0 = *(const bf16x8*)((char*)Vl + (((q5*64*2) + cb) ^ ((q5 & 7) << 4)));
            bf16x8 va1 = *(const bf16x8*)((char*)Vl + ((((32+q5)*64*2) + cb) ^ ((q5 & 7) << 4)));
            o0 = MFMA32(va0, pf[s4], o0);
            o1 = MFMA32(va1, pf[s4], o1);
        }
        __builtin_amdgcn_s_setprio(0);
    }

    // normalize + store: O^T C-layout -> lane q5 holds d = dt*32 + (r&3)+8*(r>>2)+4*hi
    const float inv = 1.f / lrun;
    const long obase = qrow*1024 + hh*64;
#pragma unroll
    for (int dt = 0; dt < 2; ++dt) {
#pragma unroll
        for (int j = 0; j < 4; ++j) {
            ushort4 pk;
            if (dt == 0) {
                pk.x = (ushort)f2bf(o0[4*j+0]*inv); pk.y = (ushort)f2bf(o0[4*j+1]*inv);
                pk.z = (ushort)f2bf(o0[4*j+2]*inv); pk.w = (ushort)f2bf(o0[4*j+3]*inv);
            } else {
                pk.x = (ushort)f2bf(o1[4*j+0]*inv); pk.y = (ushort)f2bf(o1[4*j+1]*inv);
                pk.z = (ushort)f2bf(o1[4*j+2]*inv); pk.w = (ushort)f2bf(o1[4*j+3]*inv);
            }
            *(ushort4*)(ow + obase + dt*32 + 8*j + 4*hi) = pk;
        }
    }
}

// ---------------- launch ----------------
extern "C" void kernel_launch(void* const* d_in, const int* in_sizes, int n_in,
                              void* d_out, int out_size, void* d_ws, size_t ws_size,
                              hipStream_t stream) {
    const float* query = (const float*)d_in[0];
    const float* key_  = (const float*)d_in[1];
    const float* value = (const float*)d_in[2];
    const float* Wq = (const float*)d_in[3];
    const float* bq = (const float*)d_in[4];
    const float* Wk = (const float*)d_in[5];
    const float* bk = (const float*)d_in[6];
    const float* Wv = (const float*)d_in[7];
    const float* bv = (const float*)d_in[8];
    const float* Wo = (const float*)d_in[9];
    const float* bo = (const float*)d_in[10];
    float* out = (float*)d_out;

    char* ws = (char*)d_ws;
    const size_t MB = 1u << 20;
    short* xq  = (short*)(ws);              // 8 MB  [4096][1024] bf16
    short* xk  = (short*)(ws + 8*MB);
    short* xv  = (short*)(ws + 16*MB);
    short* wqb = (short*)(ws + 24*MB);      // 2 MB each
    short* wkb = (short*)(ws + 26*MB);
    short* wvb = (short*)(ws + 28*MB);
    short* wob = (short*)(ws + 30*MB);
    short* qws = (short*)(ws + 32*MB);      // [b][s][h][d] bf16, q pre-scaled
    short* kws = (short*)(ws + 40*MB);      // [b][s][h][d]
    short* vtw = (short*)(ws + 48*MB);      // [b][h][d][s]
    float* cost = (float*)(ws + 56*MB);     // [2048][32]
    float* sint = (float*)(ws + 56*MB + 2048*32*4);
    short* attn = xq;                       // alias: xq dead after projections

    hipLaunchKernelGGL(prep_cast, dim3(2048), dim3(256), 0, stream,
                       query, key_, value, Wq, Wk, Wv, Wo,
                       xq, xk, xv, wqb, wkb, wvb, wob);
    hipLaunchKernelGGL(rope_table, dim3(256), dim3(256), 0, stream, cost, sint);
    hipLaunchKernelGGL(gemm_qkv_kernel, dim3(32, 8, 3), dim3(256), 0, stream,
                       xq, xk, xv, wqb, wkb, wvb, bq, bk, bv,
                       qws, kws, vtw, cost, sint);
    hipLaunchKernelGGL(attn_kernel, dim3(16, 16, 2), dim3(256), 0, stream,
                       qws, kws, vtw, attn);
    hipLaunchKernelGGL(gemm_o_kernel, dim3(32, 8), dim3(256), 0, stream,
                       attn, wob, bo, out);
}

// Round 5
// 225.805 us; speedup vs baseline: 1.1877x; 1.0568x over previous
//
#include <hip/hip_runtime.h>
#include <hip/hip_bf16.h>
#include <math.h>

using bf16x8 = __attribute__((ext_vector_type(8))) short;
using f32x4  = __attribute__((ext_vector_type(4))) float;
using f32x16 = __attribute__((ext_vector_type(16))) float;

#define MFMA16(a,b,c) __builtin_amdgcn_mfma_f32_16x16x32_bf16(a,b,c,0,0,0)
#define MFMA32(a,b,c) __builtin_amdgcn_mfma_f32_32x32x16_bf16(a,b,c,0,0,0)

// direct global->LDS 16B async copy; LDS dest must be wave-uniform base (+lane*16 by HW)
#define GLOAD_LDS16(g, s) __builtin_amdgcn_global_load_lds( \
    (const __attribute__((address_space(1))) unsigned int*)(const void*)(g), \
    (__attribute__((address_space(3))) unsigned int*)(void*)(s), 16, 0, 0)

static __device__ __forceinline__ short f2bf(float f) {
    __hip_bfloat16 h = __float2bfloat16(f);
    return *reinterpret_cast<short*>(&h);
}

// pack 2 f32 -> 2 bf16 in one dword (lo -> low half), RNE
static __device__ __forceinline__ int cvtpk(float lo, float hi) {
    int r;
    asm volatile("v_cvt_pk_bf16_f32 %0, %1, %2" : "=v"(r) : "v"(lo), "v"(hi));
    return r;
}

// ---------------- prep: fp32 -> bf16 casts (grid-stride over float4 units) ----------------
__global__ void prep_cast(const float* q, const float* k, const float* v,
                          const float* wq, const float* wk, const float* wv, const float* wo,
                          short* xq, short* xk, short* xv,
                          short* bwq, short* bwk, short* bwv, short* bwo) {
    const long NBIG = 1L << 20;   // 4M elems / 4
    const long NW   = 1L << 18;   // 1M elems / 4
    const long total = 3*NBIG + 4*NW;
    for (long i = (long)blockIdx.x*blockDim.x + threadIdx.x; i < total; i += (long)gridDim.x*blockDim.x) {
        const float* src; short* dst; long j = i;
        if (j < NBIG)              { src = q;  dst = xq;  }
        else if ((j -= NBIG) < NBIG) { src = k;  dst = xk;  }
        else if ((j -= NBIG) < NBIG) { src = v;  dst = xv;  }
        else if ((j -= NBIG) < NW)   { src = wq; dst = bwq; }
        else if ((j -= NW) < NW)     { src = wk; dst = bwk; }
        else if ((j -= NW) < NW)     { src = wv; dst = bwv; }
        else { j -= NW;              src = wo; dst = bwo; }
        float4 f = reinterpret_cast<const float4*>(src)[j];
        ushort4 o;
        o.x = (ushort)f2bf(f.x); o.y = (ushort)f2bf(f.y);
        o.z = (ushort)f2bf(f.z); o.w = (ushort)f2bf(f.w);
        reinterpret_cast<ushort4*>(dst)[j] = o;
    }
}

// ---------------- RoPE tables, fp64 for accuracy: cos/sin[s][j], j=0..31 ----------------
__global__ void rope_table(float* cost, float* sint) {
    int i = blockIdx.x*blockDim.x + threadIdx.x;   // 0..65535
    int s = i >> 5, j = i & 31;
    double inv = pow(10000.0, -(double)j / 32.0);
    double a = (double)s * inv;
    cost[i] = (float)cos(a);
    sint[i] = (float)sin(a);
}

// ---------------- shared 128x128x(K=1024) bf16 GEMM core: C = A * B^T ----------------
// 2-phase prefetch: dbuf LDS (passed in), issue next tile's global_load_lds BEFORE
// compute of current tile, one vmcnt(0)+barrier per K-step.
__device__ __forceinline__ void gemm_tile(const short* A, const short* B,
                                          int brow, int bcol, short* lds,
                                          f32x4 (&acc)[4][4]) {
    short* Al0 = lds;
    short* Al1 = lds + 4096;
    short* Bl0 = lds + 8192;
    short* Bl1 = lds + 12288;
    const int t = threadIdx.x;
    const int l = t & 63, qi = l & 15, h = l >> 4;
    const int w = t >> 6, wr = w >> 1, wc = w & 1;
    const f32x4 z4 = {0.f, 0.f, 0.f, 0.f};
#pragma unroll
    for (int i = 0; i < 4; ++i)
#pragma unroll
        for (int j = 0; j < 4; ++j) acc[i][j] = z4;

    const int srow = w*32 + (l >> 2);
    const int scol = (l & 3) << 3;
    const short* ga = A + (long)(brow + srow)*1024 + scol;
    const short* gb = B + (long)(bcol + srow)*1024 + scol;
    const int lo = w*32*32;   // wave-uniform LDS elem offset

    GLOAD_LDS16(ga,            Al0 + lo);
    GLOAD_LDS16(ga + 16*1024,  Al0 + lo + 16*32);
    GLOAD_LDS16(gb,            Bl0 + lo);
    GLOAD_LDS16(gb + 16*1024,  Bl0 + lo + 16*32);
    asm volatile("s_waitcnt vmcnt(0)");
    __syncthreads();

    int cur = 0;
    for (int kt = 0; kt < 32; ++kt) {
        if (kt < 31) {
            short* An = cur ? Al0 : Al1;
            short* Bn = cur ? Bl0 : Bl1;
            GLOAD_LDS16(ga + ((kt+1) << 5),            An + lo);
            GLOAD_LDS16(ga + ((kt+1) << 5) + 16*1024,  An + lo + 16*32);
            GLOAD_LDS16(gb + ((kt+1) << 5),            Bn + lo);
            GLOAD_LDS16(gb + ((kt+1) << 5) + 16*1024,  Bn + lo + 16*32);
        }
        const short* Ac = cur ? Al1 : Al0;
        const short* Bc = cur ? Bl1 : Bl0;
        bf16x8 af[4], bfr[4];
#pragma unroll
        for (int mf = 0; mf < 4; ++mf)
            af[mf] = *(const bf16x8*)(Ac + (wr*64 + mf*16 + qi)*32 + h*8);
#pragma unroll
        for (int nf = 0; nf < 4; ++nf)
            bfr[nf] = *(const bf16x8*)(Bc + (wc*64 + nf*16 + qi)*32 + h*8);
        __builtin_amdgcn_s_setprio(1);
#pragma unroll
        for (int mf = 0; mf < 4; ++mf)
#pragma unroll
            for (int nf = 0; nf < 4; ++nf)
                acc[mf][nf] = MFMA16(af[mf], bfr[nf], acc[mf][nf]);
        __builtin_amdgcn_s_setprio(0);
        asm volatile("s_waitcnt vmcnt(0)");
        __syncthreads();
        cur ^= 1;
    }
}

// ---------------- QKV projection GEMM; z selects Q/K/V; fused bias + RoPE ----------------
// Q gets 1/8 * log2(e) folded in -> attention scores arrive in log2 domain.
__global__ __launch_bounds__(256, 3)
void gemm_qkv_kernel(const short* xq, const short* xk, const short* xv,
                     const short* wq, const short* wk, const short* wv,
                     const float* biq, const float* bik, const float* biv,
                     short* qo, short* ko, short* vo,
                     const float* cost, const float* sint) {
    __shared__ __align__(16) short lds[16384];
    const int mode = blockIdx.z;
    const short* A    = mode == 0 ? xq  : (mode == 1 ? xk  : xv);
    const short* B    = mode == 0 ? wq  : (mode == 1 ? wk  : wv);
    const float* bias = mode == 0 ? biq : (mode == 1 ? bik : biv);
    const int brow = blockIdx.x * 128, bcol = blockIdx.y * 128;
    f32x4 acc[4][4];
    gemm_tile(A, B, brow, bcol, lds, acc);

    const int t = threadIdx.x;
    const int l = t & 63, qi = l & 15, h = l >> 4;
    const int w = t >> 6, wr = w >> 1, wc = w & 1;
    const int n0 = bcol + wc*64, m0 = brow + wr*64;

    if (mode < 2) {
        short* dst = mode == 0 ? qo : ko;
        const float sc = (mode == 0) ? 0.125f * 1.44269504088896f : 1.0f;
#pragma unroll
        for (int nf = 0; nf < 2; ++nf) {
            const int j = nf*16 + qi;                   // rope index 0..31 within head
            const float b0 = bias[n0 + nf*16 + qi];
            const float b1 = bias[n0 + (nf+2)*16 + qi];
#pragma unroll
            for (int mf = 0; mf < 4; ++mf) {
#pragma unroll
                for (int r = 0; r < 4; ++r) {
                    int m = m0 + mf*16 + 4*h + r;
                    int s = m & 2047;
                    float c  = cost[s*32 + j];
                    float si = sint[s*32 + j];
                    float x0 = acc[mf][nf  ][r] + b0;
                    float x1 = acc[mf][nf+2][r] + b1;
                    dst[(long)m*1024 + n0 + nf*16 + qi]      = f2bf((x0*c - x1*si) * sc);
                    dst[(long)m*1024 + n0 + (nf+2)*16 + qi]  = f2bf((x1*c + x0*si) * sc);
                }
            }
        }
    } else {
        // V: transpose 64x64 per wave through LDS, then coalesced stores to [b][h][d][s]
        __syncthreads();                    // gemm LDS free for reuse
        short* tb = lds + w*4096;           // 64x64 elems, wave-private
#pragma unroll
        for (int nf = 0; nf < 4; ++nf) {
            const int dl = nf*16 + qi;
            const float bb = bias[n0 + dl];
#pragma unroll
            for (int mf = 0; mf < 4; ++mf) {
#pragma unroll
                for (int r = 0; r < 4; ++r) {
                    const int sl = mf*16 + 4*h + r;
                    *(short*)((char*)tb + (((dl*64 + sl)*2) ^ ((dl & 7) << 4))) =
                        f2bf(acc[mf][nf][r] + bb);
                }
            }
        }
        const int hh2 = n0 >> 6;
        const int bb2 = m0 >> 11;
        const long s0g = (long)(m0 & 2047);
#pragma unroll
        for (int i = 0; i < 8; ++i) {
            const int c = l + (i << 6);
            const int dl = c >> 3, so = (c & 7) << 3;
            int4 vv = *(const int4*)((char*)tb + (((dl*64 + so)*2) ^ ((dl & 7) << 4)));
            *(int4*)(vo + (long)((bb2*16 + hh2)*64 + dl)*2048 + s0g + so) = vv;
        }
    }
}

// ---------------- O projection GEMM -> fp32 out ----------------
__global__ __launch_bounds__(256, 3)
void gemm_o_kernel(const short* A, const short* B, const float* bias, float* out) {
    __shared__ __align__(16) short lds[16384];
    const int brow = blockIdx.x * 128, bcol = blockIdx.y * 128;
    f32x4 acc[4][4];
    gemm_tile(A, B, brow, bcol, lds, acc);
    const int t = threadIdx.x;
    const int l = t & 63, qi = l & 15, h = l >> 4;
    const int w = t >> 6, wr = w >> 1, wc = w & 1;
    const int n0 = bcol + wc*64, m0 = brow + wr*64;
#pragma unroll
    for (int nf = 0; nf < 4; ++nf) {
        float bb = bias[n0 + nf*16 + qi];
#pragma unroll
        for (int mf = 0; mf < 4; ++mf) {
#pragma unroll
            for (int r = 0; r < 4; ++r) {
                int m = m0 + mf*16 + 4*h + r;
                out[(long)m*1024 + n0 + nf*16 + qi] = acc[mf][nf][r] + bb;
            }
        }
    }
}

// ---------------- flash attention, 32x32 MFMA, lane-local softmax (log2 domain) ----------------
// q,k: [b][s][h][d] bf16 (q pre-scaled by log2e/8). vT: [b][h][d][s]. out: [b][s][h][d] bf16.
// Block: 128 q rows of one (b,h); 4 waves x 32 q-rows. KV tiles of 64.
// Pipeline: dbuf LDS; issue tile jt+1 global loads at iter top (hidden under compute);
// write regs->LDS[other buf] after PV; ONE barrier per iter (see race analysis in r5 notes).
__global__ __launch_bounds__(256, 2)
void attn_kernel(const short* qw, const short* kw, const short* vtw, short* ow) {
    __shared__ __align__(16) short Kl[2][64*64];   // [kv][d], XOR-swizzled rows
    __shared__ __align__(16) short Vl[2][64*64];   // [d][kv], XOR-swizzled rows
    const int t = threadIdx.x;
    const int w = t >> 6, l = t & 63;
    const int q5 = l & 31, hi = l >> 5;
    const int b = blockIdx.z, hh = blockIdx.y;
    const long qrow = (long)b*2048 + blockIdx.x*128 + w*32 + q5;

    // Q B-frags: slab s covers d = s*16 + hi*8 + e
    bf16x8 bqf[4];
#pragma unroll
    for (int s = 0; s < 4; ++s)
        bqf[s] = *(const bf16x8*)(qw + qrow*1024 + hh*64 + s*16 + hi*8);

    f32x16 o0, o1;
#pragma unroll
    for (int r = 0; r < 16; ++r) { o0[r] = 0.f; o1[r] = 0.f; }
    float mrun = -INFINITY, lrun = 0.f;

    const short* Kg = kw  + (long)b*2048*1024 + hh*64;
    const short* Vg = vtw + (long)(b*16 + hh)*64*2048;

    // staging coords: chunk c -> row c>>3, 8-elem offset (c&7)*8
    const int r0a = t >> 3,        e0a = (t & 7) << 3;
    const int r0b = (t+256) >> 3,  e0b = ((t+256) & 7) << 3;
    const int swa = (((r0a*64 + e0a)*2) ^ ((r0a & 7) << 4));
    const int swb = (((r0b*64 + e0b)*2) ^ ((r0b & 7) << 4));

    // prologue: tile 0 -> regs -> LDS[0]
    int4 ka = *(const int4*)(Kg + (long)r0a*1024 + e0a);
    int4 va = *(const int4*)(Vg + (long)r0a*2048 + e0a);
    int4 kb = *(const int4*)(Kg + (long)r0b*1024 + e0b);
    int4 vb = *(const int4*)(Vg + (long)r0b*2048 + e0b);
    *(int4*)((char*)Kl[0] + swa) = ka;
    *(int4*)((char*)Vl[0] + swa) = va;
    *(int4*)((char*)Kl[0] + swb) = kb;
    *(int4*)((char*)Vl[0] + swb) = vb;
    __syncthreads();

    int cur = 0;
    for (int jt = 0; jt < 32; ++jt) {
        // issue next tile's loads; latency hides under QK+softmax+PV
        if (jt < 31) {
            ka = *(const int4*)(Kg + (long)((jt+1)*64 + r0a)*1024 + e0a);
            va = *(const int4*)(Vg + (long)r0a*2048 + (jt+1)*64 + e0a);
            kb = *(const int4*)(Kg + (long)((jt+1)*64 + r0b)*1024 + e0b);
            vb = *(const int4*)(Vg + (long)r0b*2048 + (jt+1)*64 + e0b);
        }
        const short* Kc = Kl[cur];
        const short* Vc = Vl[cur];

        // S^T: 2 kv-subtiles x 4 d-slabs (scores already in log2 units)
        f32x16 s0v, s1v;
#pragma unroll
        for (int r = 0; r < 16; ++r) { s0v[r] = 0.f; s1v[r] = 0.f; }
        __builtin_amdgcn_s_setprio(1);
#pragma unroll
        for (int s = 0; s < 4; ++s) {
            const int cb = (s*16 + hi*8) * 2;
            bf16x8 ka0 = *(const bf16x8*)((const char*)Kc + (((q5*64*2) + cb) ^ ((q5 & 7) << 4)));
            bf16x8 ka1 = *(const bf16x8*)((const char*)Kc + ((((32+q5)*64*2) + cb) ^ ((q5 & 7) << 4)));
            s0v = MFMA32(ka0, bqf[s], s0v);
            s1v = MFMA32(ka1, bqf[s], s1v);
        }
        __builtin_amdgcn_s_setprio(0);

        // online softmax, log2 domain; lane q5 (both hi halves) owns a q-row
        float tm = -INFINITY;
#pragma unroll
        for (int r = 0; r < 16; ++r) { tm = fmaxf(tm, s0v[r]); tm = fmaxf(tm, s1v[r]); }
        tm = fmaxf(tm, __shfl_xor(tm, 32));
        // T13 defer-max: only rescale when some row's max grew by >8 (P bounded by 2^8)
        if (!__all(tm - mrun <= 8.f)) {
            const float mnew = fmaxf(mrun, tm);
            const float corr = __builtin_amdgcn_exp2f(mrun - mnew);
#pragma unroll
            for (int r = 0; r < 16; ++r) { o0[r] *= corr; o1[r] *= corr; }
            lrun *= corr;
            mrun = mnew;
        }
        float ts = 0.f;
#pragma unroll
        for (int r = 0; r < 16; ++r) {
            s0v[r] = __builtin_amdgcn_exp2f(s0v[r] - mrun);
            s1v[r] = __builtin_amdgcn_exp2f(s1v[r] - mrun);
            ts += s0v[r] + s1v[r];
        }
        ts += __shfl_xor(ts, 32);
        lrun += ts;

        // P^T B-frags: slab s4 = 2*tt+ss covers kv = 32*tt + 16*ss + hi*8 + e
        bf16x8 pf[4];
#pragma unroll
        for (int tt = 0; tt < 2; ++tt) {
#pragma unroll
            for (int ss = 0; ss < 2; ++ss) {
                const int base = 8*ss;
                float p0, p1, p2, p3, p4, p5, p6, p7;
                if (tt == 0) {
                    p0=s0v[base+0]; p1=s0v[base+1]; p2=s0v[base+2]; p3=s0v[base+3];
                    p4=s0v[base+4]; p5=s0v[base+5]; p6=s0v[base+6]; p7=s0v[base+7];
                } else {
                    p0=s1v[base+0]; p1=s1v[base+1]; p2=s1v[base+2]; p3=s1v[base+3];
                    p4=s1v[base+4]; p5=s1v[base+5]; p6=s1v[base+6]; p7=s1v[base+7];
                }
                int X0 = cvtpk(p0, p1), Y0 = cvtpk(p2, p3);
                int X1 = cvtpk(p4, p5), Y1 = cvtpk(p6, p7);
                int sx0 = __shfl_xor(X0, 32), sy0 = __shfl_xor(Y0, 32);
                int sx1 = __shfl_xor(X1, 32), sy1 = __shfl_xor(Y1, 32);
                union { int i[4]; bf16x8 v; } u;
                u.i[0] = hi ? sx1 : X0;
                u.i[1] = hi ? sy1 : Y0;
                u.i[2] = hi ? X1  : sx0;
                u.i[3] = hi ? Y1  : sy0;
                pf[2*tt + ss] = u.v;
            }
        }

        // O^T += V^T * P^T
        __builtin_amdgcn_s_setprio(1);
#pragma unroll
        for (int s4 = 0; s4 < 4; ++s4) {
            const int cb = (s4*16 + hi*8) * 2;
            bf16x8 va0 = *(const bf16x8*)((const char*)Vc + (((q5*64*2) + cb) ^ ((q5 & 7) << 4)));
            bf16x8 va1 = *(const bf16x8*)((const char*)Vc + ((((32+q5)*64*2) + cb) ^ ((q5 & 7) << 4)));
            o0 = MFMA32(va0, pf[s4], o0);
            o1 = MFMA32(va1, pf[s4], o1);
        }
        __builtin_amdgcn_s_setprio(0);

        // write-late: stage next tile into the other buffer (all its readers are past it)
        if (jt < 31) {
            short* Kn = Kl[cur ^ 1];
            short* Vn = Vl[cur ^ 1];
            *(int4*)((char*)Kn + swa) = ka;
            *(int4*)((char*)Vn + swa) = va;
            *(int4*)((char*)Kn + swb) = kb;
            *(int4*)((char*)Vn + swb) = vb;
        }
        __syncthreads();
        cur ^= 1;
    }

    // normalize + store: O^T C-layout -> lane q5 holds d = dt*32 + (r&3)+8*(r>>2)+4*hi
    const float inv = 1.f / lrun;
    const long obase = qrow*1024 + hh*64;
#pragma unroll
    for (int dt = 0; dt < 2; ++dt) {
#pragma unroll
        for (int j = 0; j < 4; ++j) {
            ushort4 pk;
            if (dt == 0) {
                pk.x = (ushort)f2bf(o0[4*j+0]*inv); pk.y = (ushort)f2bf(o0[4*j+1]*inv);
                pk.z = (ushort)f2bf(o0[4*j+2]*inv); pk.w = (ushort)f2bf(o0[4*j+3]*inv);
            } else {
                pk.x = (ushort)f2bf(o1[4*j+0]*inv); pk.y = (ushort)f2bf(o1[4*j+1]*inv);
                pk.z = (ushort)f2bf(o1[4*j+2]*inv); pk.w = (ushort)f2bf(o1[4*j+3]*inv);
            }
            *(ushort4*)(ow + obase + dt*32 + 8*j + 4*hi) = pk;
        }
    }
}

// ---------------- launch ----------------
extern "C" void kernel_launch(void* const* d_in, const int* in_sizes, int n_in,
                              void* d_out, int out_size, void* d_ws, size_t ws_size,
                              hipStream_t stream) {
    const float* query = (const float*)d_in[0];
    const float* key_  = (const float*)d_in[1];
    const float* value = (const float*)d_in[2];
    const float* Wq = (const float*)d_in[3];
    const float* bq = (const float*)d_in[4];
    const float* Wk = (const float*)d_in[5];
    const float* bk = (const float*)d_in[6];
    const float* Wv = (const float*)d_in[7];
    const float* bv = (const float*)d_in[8];
    const float* Wo = (const float*)d_in[9];
    const float* bo = (const float*)d_in[10];
    float* out = (float*)d_out;

    char* ws = (char*)d_ws;
    const size_t MB = 1u << 20;
    short* xq  = (short*)(ws);              // 8 MB  [4096][1024] bf16
    short* xk  = (short*)(ws + 8*MB);
    short* xv  = (short*)(ws + 16*MB);
    short* wqb = (short*)(ws + 24*MB);      // 2 MB each
    short* wkb = (short*)(ws + 26*MB);
    short* wvb = (short*)(ws + 28*MB);
    short* wob = (short*)(ws + 30*MB);
    short* qws = (short*)(ws + 32*MB);      // [b][s][h][d] bf16, q pre-scaled (log2 units)
    short* kws = (short*)(ws + 40*MB);      // [b][s][h][d]
    short* vtw = (short*)(ws + 48*MB);      // [b][h][d][s]
    float* cost = (float*)(ws + 56*MB);     // [2048][32]
    float* sint = (float*)(ws + 56*MB + 2048*32*4);
    short* attn = xq;                       // alias: xq dead after projections

    hipLaunchKernelGGL(prep_cast, dim3(2048), dim3(256), 0, stream,
                       query, key_, value, Wq, Wk, Wv, Wo,
                       xq, xk, xv, wqb, wkb, wvb, wob);
    hipLaunchKernelGGL(rope_table, dim3(256), dim3(256), 0, stream, cost, sint);
    hipLaunchKernelGGL(gemm_qkv_kernel, dim3(32, 8, 3), dim3(256), 0, stream,
                       xq, xk, xv, wqb, wkb, wvb, bq, bk, bv,
                       qws, kws, vtw, cost, sint);
    hipLaunchKernelGGL(attn_kernel, dim3(16, 16, 2), dim3(256), 0, stream,
                       qws, kws, vtw, attn);
    hipLaunchKernelGGL(gemm_o_kernel, dim3(32, 8), dim3(256), 0, stream,
                       attn, wob, bo, out);
}